// Round 3
// baseline (427.795 us; speedup 1.0000x reference)
//
#include <hip/hip_runtime.h>
#include <hip/hip_bf16.h>

// Swin-V2 window attention, fused one-block-per-window.
// B=32, H=W=64, C=60, NH=6, hd=10, WS=7, pad->70, nw=10, 3200 windows x 49 tokens.
//
// R2 post-mortem: NaN persisted after removing all LDS UB -> dtype assumption
// itself is suspect. This round runtime-detects fp32 vs bf16 input encoding
// (reading fp32 data as bf16 gives garbage exponents at even indices) and
// launches both templated variants; each early-exits unless the flag matches.

#define NHEADS 6
#define WSZ 7
#define NT 49
#define CH 60
#define IMG 64
#define LOG100F 4.605170185988092f

__device__ __forceinline__ float b2f(unsigned short u) {
    union { unsigned int i; float f; } v;
    v.i = ((unsigned int)u) << 16;
    return v.f;
}

__device__ __forceinline__ float cvt(float v) { return v; }
__device__ __forceinline__ float cvt(__hip_bfloat16 v) { return __bfloat162float(v); }

template <typename T>
__device__ __forceinline__ void stv(T* p, float v);
template <> __device__ __forceinline__ void stv<float>(float* p, float v) { *p = v; }
template <> __device__ __forceinline__ void stv<__hip_bfloat16>(__hip_bfloat16* p, float v) { *p = __float2bfloat16(v); }

// load 4 consecutive weights as fp32
template <typename T>
__device__ __forceinline__ void loadw4(const T* p, float& a, float& b, float& c, float& d) {
    if constexpr (sizeof(T) == 2) {
        const ushort4 wv = *reinterpret_cast<const ushort4*>((const void*)p);
        a = b2f(wv.x); b = b2f(wv.y); c = b2f(wv.z); d = b2f(wv.w);
    } else {
        const float4 wv = *reinterpret_cast<const float4*>((const void*)p);
        a = wv.x; b = wv.y; c = wv.z; d = wv.w;
    }
}

// Detector: bf16-view even indices of x. True bf16 N(0,1): exp field < 140 always.
// fp32 misread: even elements are float low-halves -> exp field ~uniform, ~45% >= 140.
__global__ void detect_fp32(const unsigned short* __restrict__ xr, int* __restrict__ flag) {
    int lane = threadIdx.x;              // 64 threads
    unsigned short u = xr[2 * lane];
    int e = (u >> 7) & 0xFF;
    unsigned long long m = __ballot(e >= 140);
    if (lane == 0) *flag = (__popcll(m) > 16) ? 1 : 0;   // 1 => inputs are fp32
}

template <typename T, int WANT>
__global__ __launch_bounds__(256, 2)
void swin_win_attn(const T* __restrict__ x,
                   const T* __restrict__ qkv_w,
                   const T* __restrict__ qkv_b,
                   const T* __restrict__ logit_scale,
                   const T* __restrict__ proj_w,
                   const T* __restrict__ proj_b,
                   T* __restrict__ out,
                   const int* __restrict__ flag)
{
    if (*flag != WANT) return;

    __shared__ __align__(16) float s_x[NT * 68];          // 49 x 68; doubles as s_out
    __shared__ __align__(16) float s_q[NHEADS * NT * 11];
    __shared__ __align__(16) float s_k[NHEADS * NT * 12]; // 48B rows, float4
    __shared__ __align__(16) float s_v[NHEADS * NT * 12];

    const int tid = threadIdx.x;
    const int w  = blockIdx.x;
    const int b  = w / 100;
    const int wy = (w / 10) % 10;
    const int wx = w % 10;
    const int row0 = wy * WSZ;
    const int col0 = wx * WSZ;

    // ---- Phase 1: stage x window tile (zero-padded outside image) ----
    for (int idx = tid; idx < NT * CH; idx += 256) {
        int t = idx / CH, c = idx - t * CH;
        int r  = row0 + t / WSZ;
        int cc = col0 + t % WSZ;
        float v = 0.f;
        if (r < IMG && cc < IMG)
            v = cvt(x[((b * IMG + r) * IMG + cc) * CH + c]);
        s_x[t * 68 + c] = v;
    }
    __syncthreads();

    // ---- Phase 2: qkv = x @ W^T + b ----
    for (int item = tid; item < 18 * NT; item += 256) {
        int og = item / NT, t = item - og * NT;
        int part = og / NHEADS, h = og - part * NHEADS;
        int obase = og * 10;   // == part*60 + h*10
        float acc[10];
        #pragma unroll
        for (int u = 0; u < 10; ++u) acc[u] = cvt(qkv_b[obase + u]);
        const float4* xr = reinterpret_cast<const float4*>(s_x + t * 68);
        #pragma unroll
        for (int m = 0; m < 15; ++m) {
            float4 xv = xr[m];
            #pragma unroll
            for (int u = 0; u < 10; ++u) {
                float wa, wb, wc, wd;
                loadw4(qkv_w + (obase + u) * CH + 4 * m, wa, wb, wc, wd);
                acc[u] += xv.x * wa + xv.y * wb + xv.z * wc + xv.w * wd;
            }
        }
        int rrow = h * NT + t;
        if (part == 0) {
            #pragma unroll
            for (int u = 0; u < 10; ++u) s_q[rrow * 11 + u] = acc[u];
        } else if (part == 1) {
            #pragma unroll
            for (int u = 0; u < 10; ++u) s_k[rrow * 12 + u] = acc[u];
            s_k[rrow * 12 + 10] = 0.f;
            s_k[rrow * 12 + 11] = 0.f;
        } else {
            #pragma unroll
            for (int u = 0; u < 10; ++u) s_v[rrow * 12 + u] = acc[u];
            s_v[rrow * 12 + 10] = 0.f;
            s_v[rrow * 12 + 11] = 0.f;
        }
    }
    __syncthreads();

    // ---- Phase 3: L2-normalize q and k rows (clamped at 1e-12) ----
    for (int item = tid; item < 2 * NHEADS * NT; item += 256) {
        int which = item / (NHEADS * NT);
        int r = item - which * (NHEADS * NT);
        float* p = (which == 0) ? (s_q + r * 11) : (s_k + r * 12);
        float ss = 0.f;
        #pragma unroll
        for (int d = 0; d < 10; ++d) ss += p[d] * p[d];
        float inv = 1.f / fmaxf(sqrtf(ss), 1e-12f);
        #pragma unroll
        for (int d = 0; d < 10; ++d) p[d] *= inv;
    }
    __syncthreads();

    // ---- Phase 4: fused attention, one (head,row) per thread ----
    for (int r = tid; r < NHEADS * NT; r += 256) {
        int h = r / NT, i = r - h * NT;
        float scale = __expf(fminf(cvt(logit_scale[h]), LOG100F));
        float q[10];
        #pragma unroll
        for (int d = 0; d < 10; ++d) q[d] = s_q[r * 11 + d];
        float a[NT];
        const float4* kb = reinterpret_cast<const float4*>(s_k) + (h * NT) * 3;
        #pragma unroll
        for (int j = 0; j < NT; ++j) {
            float4 k0 = kb[j * 3 + 0];
            float4 k1 = kb[j * 3 + 1];
            float4 k2 = kb[j * 3 + 2];
            float dp = q[0]*k0.x + q[1]*k0.y + q[2]*k0.z + q[3]*k0.w
                     + q[4]*k1.x + q[5]*k1.y + q[6]*k1.z + q[7]*k1.w
                     + q[8]*k2.x + q[9]*k2.y;
            a[j] = dp * scale;
        }
        float m = a[0];
        #pragma unroll
        for (int j = 1; j < NT; ++j) m = fmaxf(m, a[j]);
        float s = 0.f;
        #pragma unroll
        for (int j = 0; j < NT; ++j) { float e = __expf(a[j] - m); a[j] = e; s += e; }
        float inv = 1.f / s;
        float o[10];
        #pragma unroll
        for (int d = 0; d < 10; ++d) o[d] = 0.f;
        const float4* vb = reinterpret_cast<const float4*>(s_v) + (h * NT) * 3;
        #pragma unroll
        for (int j = 0; j < NT; ++j) {
            float4 v0 = vb[j * 3 + 0];
            float4 v1 = vb[j * 3 + 1];
            float4 v2 = vb[j * 3 + 2];
            float aj = a[j] * inv;
            o[0] += aj * v0.x; o[1] += aj * v0.y; o[2] += aj * v0.z; o[3] += aj * v0.w;
            o[4] += aj * v1.x; o[5] += aj * v1.y; o[6] += aj * v1.z; o[7] += aj * v1.w;
            o[8] += aj * v2.x; o[9] += aj * v2.y;
        }
        #pragma unroll
        for (int d = 0; d < 10; ++d) s_x[i * 68 + h * 10 + d] = o[d];
    }
    __syncthreads();

    // ---- Phase 5: projection + scatter valid tokens ----
    for (int item = tid; item < 6 * NT; item += 256) {
        int cg = item / NT, t = item - cg * NT;
        float acc[10];
        #pragma unroll
        for (int u = 0; u < 10; ++u) acc[u] = cvt(proj_b[cg * 10 + u]);
        const float4* xr = reinterpret_cast<const float4*>(s_x + t * 68);
        #pragma unroll
        for (int m = 0; m < 15; ++m) {
            float4 xv = xr[m];
            #pragma unroll
            for (int u = 0; u < 10; ++u) {
                float wa, wb, wc, wd;
                loadw4(proj_w + (cg * 10 + u) * CH + 4 * m, wa, wb, wc, wd);
                acc[u] += xv.x * wa + xv.y * wb + xv.z * wc + xv.w * wd;
            }
        }
        int r  = row0 + t / WSZ;
        int cc = col0 + t % WSZ;
        if (r < IMG && cc < IMG) {
            T* op = out + ((b * IMG + r) * IMG + cc) * CH + cg * 10;
            #pragma unroll
            for (int u = 0; u < 10; ++u) stv(op + u, acc[u]);
        }
    }
}

extern "C" void kernel_launch(void* const* d_in, const int* in_sizes, int n_in,
                              void* d_out, int out_size, void* d_ws, size_t ws_size,
                              hipStream_t stream) {
    int* flag = (int*)d_ws;
    hipLaunchKernelGGL(detect_fp32, dim3(1), dim3(64), 0, stream,
                       (const unsigned short*)d_in[0], flag);

    // fp32 variant (WANT=1)
    hipLaunchKernelGGL((swin_win_attn<float, 1>), dim3(3200), dim3(256), 0, stream,
                       (const float*)d_in[0], (const float*)d_in[1],
                       (const float*)d_in[2], (const float*)d_in[3],
                       (const float*)d_in[4], (const float*)d_in[5],
                       (float*)d_out, flag);

    // bf16 variant (WANT=0)
    hipLaunchKernelGGL((swin_win_attn<__hip_bfloat16, 0>), dim3(3200), dim3(256), 0, stream,
                       (const __hip_bfloat16*)d_in[0], (const __hip_bfloat16*)d_in[1],
                       (const __hip_bfloat16*)d_in[2], (const __hip_bfloat16*)d_in[3],
                       (const __hip_bfloat16*)d_in[4], (const __hip_bfloat16*)d_in[5],
                       (__hip_bfloat16*)d_out, flag);
}

// Round 4
// 344.124 us; speedup vs baseline: 1.2431x; 1.2431x over previous
//
#include <hip/hip_runtime.h>
#include <hip/hip_bf16.h>

// Swin-V2 window attention, fused one-block-per-window. All I/O is fp32
// (established R3: R2 kernel == R3 bf16 variant NaN'd, fp32 variant passed).
// B=32, H=W=64, C=60, NH=6, hd=10, WS=7 -> pad 70, nw=10, 3200 windows x 49 tok.
//
// R4: latency-bound fix. Phases 2/5 make weight addresses wave-uniform
// (og/cg from readfirstlane(tid>>6), lanes = tokens) so the compiler emits
// s_load for weights (scalar pipe, no VGPR cost); LDS trimmed to 53,312 B
// for 3 blocks/CU.

#define NHEADS 6
#define WSZ 7
#define NT 49
#define CH 60
#define IMG 64
#define LOG100F 4.605170185988092f

__global__ __launch_bounds__(256, 3)
void swin_win_attn(const float* __restrict__ x,
                   const float* __restrict__ qkv_w,
                   const float* __restrict__ qkv_b,
                   const float* __restrict__ logit_scale,
                   const float* __restrict__ proj_w,
                   const float* __restrict__ proj_b,
                   float* __restrict__ out)
{
    __shared__ __align__(16) float s_x[NT * 68];           // 3332 f; doubles as s_out
    __shared__ __align__(16) float s_q[NHEADS * NT * 10];  // 2940 f (stride 10: 2-way, free)
    __shared__ __align__(16) float s_k[NHEADS * NT * 12];  // 3528 f (48B rows, float4)
    __shared__ __align__(16) float s_v[NHEADS * NT * 12];  // 3528 f  => 53,312 B total

    const int tid  = threadIdx.x;
    const int lane = tid & 63;
    const int wid  = __builtin_amdgcn_readfirstlane(tid >> 6);  // provably wave-uniform
    const int w  = blockIdx.x;
    const int b  = w / 100;
    const int wy = (w / 10) % 10;
    const int wx = w % 10;
    const int row0 = wy * WSZ;
    const int col0 = wx * WSZ;

    // ---- Phase 1: stage x window tile as float4 (rows 16B-aligned: 60%4==0) ----
    for (int idx = tid; idx < NT * 15; idx += 256) {
        int t = idx / 15, mi = idx - t * 15;
        int r  = row0 + t / WSZ;
        int cc = col0 + t % WSZ;
        float4 v = make_float4(0.f, 0.f, 0.f, 0.f);
        if (r < IMG && cc < IMG)
            v = reinterpret_cast<const float4*>(x + ((b * IMG + r) * IMG + cc) * CH)[mi];
        *reinterpret_cast<float4*>(s_x + t * 68 + 4 * mi) = v;
    }
    __syncthreads();

    // ---- Phase 2: qkv = x @ W^T + b. og wave-uniform -> weights via s_load ----
    {
        const int tt = (lane < NT) ? lane : NT - 1;
        const float4* xr = reinterpret_cast<const float4*>(s_x + tt * 68);
        for (int og = wid; og < 18; og += 4) {
            const int part = og / NHEADS;
            const int h = og - part * NHEADS;
            const float* wb = qkv_w + og * 10 * CH;   // uniform
            float acc[10];
            #pragma unroll
            for (int u = 0; u < 10; ++u) acc[u] = qkv_b[og * 10 + u];  // uniform
            for (int m = 0; m < 15; ++m) {
                float4 xv = xr[m];
                #pragma unroll
                for (int u = 0; u < 10; ++u) {
                    float4 wv = *reinterpret_cast<const float4*>(wb + u * CH + 4 * m);
                    acc[u] += xv.x * wv.x + xv.y * wv.y + xv.z * wv.z + xv.w * wv.w;
                }
            }
            if (lane < NT) {
                int rrow = h * NT + lane;
                if (part == 0) {
                    #pragma unroll
                    for (int u = 0; u < 10; ++u) s_q[rrow * 10 + u] = acc[u];
                } else if (part == 1) {
                    #pragma unroll
                    for (int u = 0; u < 10; ++u) s_k[rrow * 12 + u] = acc[u];
                    s_k[rrow * 12 + 10] = 0.f;
                    s_k[rrow * 12 + 11] = 0.f;
                } else {
                    #pragma unroll
                    for (int u = 0; u < 10; ++u) s_v[rrow * 12 + u] = acc[u];
                    s_v[rrow * 12 + 10] = 0.f;
                    s_v[rrow * 12 + 11] = 0.f;
                }
            }
        }
    }
    __syncthreads();

    // ---- Phase 3: L2-normalize q and k rows (clamped at 1e-12) ----
    for (int item = tid; item < 2 * NHEADS * NT; item += 256) {
        int which = item / (NHEADS * NT);
        int r = item - which * (NHEADS * NT);
        float* p = (which == 0) ? (s_q + r * 10) : (s_k + r * 12);
        float ss = 0.f;
        #pragma unroll
        for (int d = 0; d < 10; ++d) ss += p[d] * p[d];
        float inv = 1.f / fmaxf(sqrtf(ss), 1e-12f);
        #pragma unroll
        for (int d = 0; d < 10; ++d) p[d] *= inv;
    }
    __syncthreads();

    // ---- Phase 4: fused attention, one (head,row) per thread ----
    for (int r = tid; r < NHEADS * NT; r += 256) {
        int h = r / NT, i = r - h * NT;
        float scale = __expf(fminf(logit_scale[h], LOG100F));
        float q[10];
        #pragma unroll
        for (int d = 0; d < 10; ++d) q[d] = s_q[r * 10 + d];
        float a[NT];
        const float4* kb = reinterpret_cast<const float4*>(s_k) + (h * NT) * 3;
        #pragma unroll
        for (int j = 0; j < NT; ++j) {
            float4 k0 = kb[j * 3 + 0];
            float4 k1 = kb[j * 3 + 1];
            float4 k2 = kb[j * 3 + 2];   // .z,.w zeroed pads
            float dp = q[0]*k0.x + q[1]*k0.y + q[2]*k0.z + q[3]*k0.w
                     + q[4]*k1.x + q[5]*k1.y + q[6]*k1.z + q[7]*k1.w
                     + q[8]*k2.x + q[9]*k2.y;
            a[j] = dp * scale;
        }
        float m = a[0];
        #pragma unroll
        for (int j = 1; j < NT; ++j) m = fmaxf(m, a[j]);
        float s = 0.f;
        #pragma unroll
        for (int j = 0; j < NT; ++j) { float e = __expf(a[j] - m); a[j] = e; s += e; }
        float o[10];
        #pragma unroll
        for (int d = 0; d < 10; ++d) o[d] = 0.f;
        const float4* vb = reinterpret_cast<const float4*>(s_v) + (h * NT) * 3;
        #pragma unroll
        for (int j = 0; j < NT; ++j) {
            float4 v0 = vb[j * 3 + 0];
            float4 v1 = vb[j * 3 + 1];
            float4 v2 = vb[j * 3 + 2];
            float aj = a[j];
            o[0] += aj * v0.x; o[1] += aj * v0.y; o[2] += aj * v0.z; o[3] += aj * v0.w;
            o[4] += aj * v1.x; o[5] += aj * v1.y; o[6] += aj * v1.z; o[7] += aj * v1.w;
            o[8] += aj * v2.x; o[9] += aj * v2.y;
        }
        float inv = 1.f / s;   // fold softmax denom into final scale (10 mults not 49)
        #pragma unroll
        for (int d = 0; d < 10; ++d) s_x[i * 68 + h * 10 + d] = o[d] * inv;
    }
    __syncthreads();

    // ---- Phase 5: projection (cg wave-uniform -> s_load weights) + scatter ----
    {
        const int tt = (lane < NT) ? lane : NT - 1;
        const int r  = row0 + tt / WSZ;
        const int cc = col0 + tt % WSZ;
        const bool valid = (lane < NT) && (r < IMG) && (cc < IMG);
        const float4* xr = reinterpret_cast<const float4*>(s_x + tt * 68);
        for (int cg = wid; cg < NHEADS; cg += 4) {
            const float* wb = proj_w + cg * 10 * CH;   // uniform
            float acc[10];
            #pragma unroll
            for (int u = 0; u < 10; ++u) acc[u] = proj_b[cg * 10 + u];  // uniform
            for (int m = 0; m < 15; ++m) {
                float4 xv = xr[m];
                #pragma unroll
                for (int u = 0; u < 10; ++u) {
                    float4 wv = *reinterpret_cast<const float4*>(wb + u * CH + 4 * m);
                    acc[u] += xv.x * wv.x + xv.y * wv.y + xv.z * wv.z + xv.w * wv.w;
                }
            }
            if (valid) {
                float* op = out + ((b * IMG + r) * IMG + cc) * CH + cg * 10;
                #pragma unroll
                for (int u = 0; u < 5; ++u)   // 8B-aligned float2 stores
                    *reinterpret_cast<float2*>(op + 2 * u) =
                        make_float2(acc[2 * u], acc[2 * u + 1]);
            }
        }
    }
}

extern "C" void kernel_launch(void* const* d_in, const int* in_sizes, int n_in,
                              void* d_out, int out_size, void* d_ws, size_t ws_size,
                              hipStream_t stream) {
    hipLaunchKernelGGL(swin_win_attn, dim3(3200), dim3(256), 0, stream,
                       (const float*)d_in[0], (const float*)d_in[1],
                       (const float*)d_in[2], (const float*)d_in[3],
                       (const float*)d_in[4], (const float*)d_in[5],
                       (float*)d_out);
}